// Round 1
// baseline (4298.640 us; speedup 1.0000x reference)
//
#include <hip/hip_runtime.h>

// GRUModel: 2-layer GRU (H=64), B=4096, T=512, input dim 1, fp32.
// Mapping: lane <-> hidden unit (64 lanes = 64 units), wave <-> NB=4 batch
// elements, 4 waves/block, 256 blocks -> 1024 waves = 1 wave/SIMD on 256 CUs.
// Weights transposed in LDS (lane-consecutive b32 reads, conflict-free).
// Hidden state per wave in LDS [j][4elems] -> uniform float4 broadcast reads.
// No __syncthreads in the time loop: each wave owns its 4 batch elements.

#define T_LEN 512
#define NB 4

__device__ __forceinline__ float sigm(float x) {
    return 1.0f / (1.0f + __expf(-x));
}
__device__ __forceinline__ float tanh_fast(float x) {
    // tanh(x) = 2/(1+exp(-2x)) - 1
    return 2.0f / (1.0f + __expf(-2.0f * x)) - 1.0f;
}

__global__ __launch_bounds__(256, 1)
void gru_fused(const float* __restrict__ x,      // [B, T]
               const float* __restrict__ w_ih0,  // [192]
               const float* __restrict__ w_hh0,  // [192,64]
               const float* __restrict__ b_ih0,  // [192]
               const float* __restrict__ b_hh0,  // [192]
               const float* __restrict__ w_ih1,  // [192,64]
               const float* __restrict__ w_hh1,  // [192,64]
               const float* __restrict__ b_ih1,  // [192]
               const float* __restrict__ b_hh1,  // [192]
               const float* __restrict__ fc_w,   // [64]
               const float* __restrict__ fc_b,   // [1]
               float* __restrict__ out)          // [B]
{
    extern __shared__ float lds[];
    float* lw = lds;  // [3][64][192]: lw[(s*64+j)*192 + c] = W_s[c][j]

    const int tid  = threadIdx.x;
    const int lane = tid & 63;
    const int wv   = tid >> 6;

    float* h0l = lds + 3 * 64 * 192 + wv * 512;  // [64][NB]
    float* h1l = h0l + 256;                      // [64][NB]

    // ---- stage transposed weights into LDS (coalesced global reads) ----
    for (int idx = tid; idx < 12288; idx += 256) {
        const int c = idx >> 6;       // row (gate*64+i) in original [192,64]
        const int j = idx & 63;       // col
        const int dst = j * 192 + c;
        lw[dst]          = w_hh0[idx];
        lw[12288 + dst]  = w_ih1[idx];
        lw[24576 + dst]  = w_hh1[idx];
    }
    // init hidden state
    #pragma unroll
    for (int e = 0; e < NB; e++) { h0l[lane * NB + e] = 0.f; h1l[lane * NB + e] = 0.f; }
    __syncthreads();

    // per-lane constants (lane i owns gate rows {i, 64+i, 128+i})
    float wi0[3], bi0[3], bh0[3], bi1[3], bh1[3];
    #pragma unroll
    for (int g = 0; g < 3; g++) {
        wi0[g] = w_ih0[g * 64 + lane];
        bi0[g] = b_ih0[g * 64 + lane];
        bh0[g] = b_hh0[g * 64 + lane];
        bi1[g] = b_ih1[g * 64 + lane];
        bh1[g] = b_hh1[g * 64 + lane];
    }

    const int e0 = (blockIdx.x * 4 + wv) * NB;   // first batch elem of wave
    const float* xr0 = x + (size_t)e0 * T_LEN;

    float h0r[NB] = {0.f, 0.f, 0.f, 0.f};
    float h1r[NB] = {0.f, 0.f, 0.f, 0.f};

    for (int t = 0; t < T_LEN; t++) {
        float xv[NB];
        #pragma unroll
        for (int e = 0; e < NB; e++) xv[e] = xr0[e * T_LEN + t];

        // ======== layer 0: gh0 = W_hh0 @ h0 ========
        float ar[NB] = {0.f,0.f,0.f,0.f};
        float az[NB] = {0.f,0.f,0.f,0.f};
        float an[NB] = {0.f,0.f,0.f,0.f};
        #pragma unroll 8
        for (int j = 0; j < 64; j++) {
            const float* wj = lw + j * 192;
            const float wr = wj[lane];
            const float wz = wj[64 + lane];
            const float wn = wj[128 + lane];
            const float4 h4 = *(const float4*)(h0l + j * 4);
            const float hh[4] = {h4.x, h4.y, h4.z, h4.w};
            #pragma unroll
            for (int e = 0; e < NB; e++) {
                ar[e] = fmaf(wr, hh[e], ar[e]);
                az[e] = fmaf(wz, hh[e], az[e]);
                an[e] = fmaf(wn, hh[e], an[e]);
            }
        }
        float h0n[NB];
        #pragma unroll
        for (int e = 0; e < NB; e++) {
            const float r = sigm(fmaf(xv[e], wi0[0], bi0[0]) + ar[e] + bh0[0]);
            const float z = sigm(fmaf(xv[e], wi0[1], bi0[1]) + az[e] + bh0[1]);
            const float n = tanh_fast(fmaf(xv[e], wi0[2], bi0[2]) + r * (an[e] + bh0[2]));
            h0n[e] = n + z * (h0r[e] - n);
            h0r[e] = h0n[e];
        }
        *(float4*)(h0l + lane * 4) = make_float4(h0n[0], h0n[1], h0n[2], h0n[3]);
        __builtin_amdgcn_wave_barrier();  // pin order: write h0 before layer-1 reads

        // ======== layer 1: gi1 = W_ih1 @ h0new, gh1 = W_hh1 @ h1 ========
        float br[NB] = {0.f,0.f,0.f,0.f};
        float bz[NB] = {0.f,0.f,0.f,0.f};
        float bn[NB] = {0.f,0.f,0.f,0.f};
        float cr[NB] = {0.f,0.f,0.f,0.f};
        float cz[NB] = {0.f,0.f,0.f,0.f};
        float cn[NB] = {0.f,0.f,0.f,0.f};
        #pragma unroll 8
        for (int j = 0; j < 64; j++) {
            const float* wi = lw + 12288 + j * 192;
            const float* wh = lw + 24576 + j * 192;
            const float ir_ = wi[lane];
            const float iz_ = wi[64 + lane];
            const float in_ = wi[128 + lane];
            const float hr_ = wh[lane];
            const float hz_ = wh[64 + lane];
            const float hn_ = wh[128 + lane];
            const float4 g4 = *(const float4*)(h0l + j * 4);
            const float4 q4 = *(const float4*)(h1l + j * 4);
            const float gg[4] = {g4.x, g4.y, g4.z, g4.w};
            const float qq[4] = {q4.x, q4.y, q4.z, q4.w};
            #pragma unroll
            for (int e = 0; e < NB; e++) {
                br[e] = fmaf(ir_, gg[e], br[e]);
                bz[e] = fmaf(iz_, gg[e], bz[e]);
                bn[e] = fmaf(in_, gg[e], bn[e]);
                cr[e] = fmaf(hr_, qq[e], cr[e]);
                cz[e] = fmaf(hz_, qq[e], cz[e]);
                cn[e] = fmaf(hn_, qq[e], cn[e]);
            }
        }
        float h1n[NB];
        #pragma unroll
        for (int e = 0; e < NB; e++) {
            const float r = sigm(br[e] + bi1[0] + cr[e] + bh1[0]);
            const float z = sigm(bz[e] + bi1[1] + cz[e] + bh1[1]);
            const float n = tanh_fast(bn[e] + bi1[2] + r * (cn[e] + bh1[2]));
            h1n[e] = n + z * (h1r[e] - n);
            h1r[e] = h1n[e];
        }
        *(float4*)(h1l + lane * 4) = make_float4(h1n[0], h1n[1], h1n[2], h1n[3]);
        __builtin_amdgcn_wave_barrier();
    }

    // ======== final FC: out[b] = sum_i fc_w[i] * h1[b, i] + fc_b ========
    const float fw = fc_w[lane];
    const float fb = fc_b[0];
    #pragma unroll
    for (int e = 0; e < NB; e++) {
        float v = fw * h1r[e];
        #pragma unroll
        for (int off = 32; off > 0; off >>= 1)
            v += __shfl_xor(v, off, 64);
        if (lane == 0) out[e0 + e] = v + fb;
    }
}

extern "C" void kernel_launch(void* const* d_in, const int* in_sizes, int n_in,
                              void* d_out, int out_size, void* d_ws, size_t ws_size,
                              hipStream_t stream)
{
    const float* x     = (const float*)d_in[0];
    const float* w_ih0 = (const float*)d_in[1];
    const float* w_hh0 = (const float*)d_in[2];
    const float* b_ih0 = (const float*)d_in[3];
    const float* b_hh0 = (const float*)d_in[4];
    const float* w_ih1 = (const float*)d_in[5];
    const float* w_hh1 = (const float*)d_in[6];
    const float* b_ih1 = (const float*)d_in[7];
    const float* b_hh1 = (const float*)d_in[8];
    const float* fc_w  = (const float*)d_in[9];
    const float* fc_b  = (const float*)d_in[10];
    float* out = (float*)d_out;

    // 144 KB transposed weights + 8 KB hidden state = 152 KB dynamic LDS
    const size_t shmem = (size_t)(3 * 64 * 192 + 4 * 512) * sizeof(float);
    // opt-in for >64 KB dynamic LDS (idempotent, host-side, capture-safe)
    (void)hipFuncSetAttribute((const void*)gru_fused,
                              hipFuncAttributeMaxDynamicSharedMemorySize,
                              (int)shmem);

    hipLaunchKernelGGL(gru_fused, dim3(256), dim3(256), shmem, stream,
                       x, w_ih0, w_hh0, b_ih0, b_hh0,
                       w_ih1, w_hh1, b_ih1, b_hh1, fc_w, fc_b, out);
}